// Round 8
// baseline (155.447 us; speedup 1.0000x reference)
//
#include <hip/hip_runtime.h>
#include <hip/hip_bf16.h>
#include <stdint.h>

// ContrastiveLoss: N=8192, D=512 fp32 features, int labels {0,1}.
// out = mean_i [ (np_i * log(sum_exp_i) - sum_pos_i) / (np_i + 1e-8) ]
// R1..R19: fp8 128^2 tiles, upper-tri, XCD swizzle, gload_lds, [slot][row]
//     PEP, DPP epilogue. 109.5 us (sim ~45).
// R22: MX 32x32x64 correct but bank-conflicted (-11). R23: transposed
//     f8t[unit][row][16B] + unit-major LDS + MX 16x16x128: conflicts gone,
//     107.4 us champion, sim ~43.
// Post-R23 insight: sim stuck 43-56 across MFMA density/conflict/pipeline
//     changes; pipe-busy sums (MFMA 7 + VALU ~16 + LDS ~14) << 43 us.
//     Barrier-lockstep convoy + per-block fixed costs dominate:
//     12.7k cyc/block-slot vs ~6.5k of work, paid 2080 times.
// R24: amortize 4x -- 256^2 tiles (m201 geometry): 528 blocks (=8*66),
//     8 waves (2x4), each 128x64 out (8x4 MFMA 16x16x128), BK=128,
//     128KB dynamic LDS double-buffer (1 block/CU). Reused av register ->
//     per-m {2 ds_read -> 4 MFMA} fine interleave. Slot algebra:
//     slotR=4*bj+wn, slotC=4*bi+2*wm+h (h=m>>2); disjoint, 128/row exact.

#define N_ROWS 8192
#define DIMF 512
#define DIMB 512
#define NB2 32
#define NSLOT 128
#define SIM_SCALE 0.0390625f   // 10 / 256  (features pre-scaled by 16)
#define UST (8192 * 16)        // f8t unit stride: one 16B unit for all rows

typedef float f32x4 __attribute__((ext_vector_type(4)));
typedef int i32x4 __attribute__((ext_vector_type(4)));
typedef int i32x8 __attribute__((ext_vector_type(8)));

__device__ static inline void gload_lds16(const uint8_t* g, uint8_t* l) {
    __builtin_amdgcn_global_load_lds(
        (const __attribute__((address_space(1))) unsigned int*)g,
        (__attribute__((address_space(3))) unsigned int*)l, 16, 0, 0);
}

// 16-lane rotate-reduce (VALU DPP row_ror, no LDS pipe). Proven R19.
__device__ static inline float rowsum16(float s) {
    s += __int_as_float(__builtin_amdgcn_update_dpp(
        0, __float_as_int(s), 0x128, 0xf, 0xf, false));
    s += __int_as_float(__builtin_amdgcn_update_dpp(
        0, __float_as_int(s), 0x124, 0xf, 0xf, false));
    s += __int_as_float(__builtin_amdgcn_update_dpp(
        0, __float_as_int(s), 0x122, 0xf, 0xf, false));
    s += __int_as_float(__builtin_amdgcn_update_dpp(
        0, __float_as_int(s), 0x121, 0xf, 0xf, false));
    return s;
}

// 4 waves/block, one row per wave: fp32 sumsq -> scale by 16/norm -> fp8.
// Output layout: f8t[g][row][16B], g = dim>>4 (unit-major transposed).
__global__ __launch_bounds__(256) void norm_kernel(const float* __restrict__ x,
                                                   uint8_t* __restrict__ f8t,
                                                   float* __restrict__ out) {
    const int wave = threadIdx.x >> 6, t = threadIdx.x & 63;
    const int row = blockIdx.x * 4 + wave;
    const float4* xr = (const float4*)(x + (size_t)row * DIMF);
    float4 v0 = xr[2 * t];
    float4 v1 = xr[2 * t + 1];
    float ss = v0.x * v0.x + v0.y * v0.y + v0.z * v0.z + v0.w * v0.w +
               v1.x * v1.x + v1.y * v1.y + v1.z * v1.z + v1.w * v1.w;
#pragma unroll
    for (int off = 32; off >= 1; off >>= 1) ss += __shfl_xor(ss, off, 64);
    float s = 16.0f / fmaxf(sqrtf(ss), 1e-12f);
    int lo = 0, hi = 0;
    lo = __builtin_amdgcn_cvt_pk_fp8_f32(v0.x * s, v0.y * s, lo, false);
    lo = __builtin_amdgcn_cvt_pk_fp8_f32(v0.z * s, v0.w * s, lo, true);
    hi = __builtin_amdgcn_cvt_pk_fp8_f32(v1.x * s, v1.y * s, hi, false);
    hi = __builtin_amdgcn_cvt_pk_fp8_f32(v1.z * s, v1.w * s, hi, true);
    int2 pk;
    pk.x = lo;
    pk.y = hi;
    *(int2*)(f8t + (size_t)(t >> 1) * UST + (size_t)row * 16 + (t & 1) * 8) = pk;
    if (blockIdx.x == 0 && threadIdx.x == 0) out[0] = 0.0f;
}

// 256x256 tile/block, 8 waves (2x4), each 128x64 via 8x4 MFMA 16x16x128
// MX-fp8 (uniform 1.0 E8M0 scales -> exact; A/B operand symmetry makes any
// consistent k-mapping exact). BK=128B (8 units/step, 4 steps), 2-buffer
// __syncthreads pipeline, 128KB dynamic LDS: per buffer [8 units][512
// rows][16B] (rows 0-255 = A-tile, 256-511 = B-tile). Staging: wave w
// stages rows w*64..w*64+63 of the combined space for all 8 units --
// contiguous 1024B wave-writes. Fragment reads: contiguous 16B/lane over
// rows (2-way bank tier, free).
__global__ __launch_bounds__(512) void sim_kernel(const uint8_t* __restrict__ f8t,
                                                  const int* __restrict__ lab,
                                                  float2* __restrict__ PEP) {
    extern __shared__ uint8_t smem[];

    // XCD-locality swizzle (528 = 8 * 66); decode upper-triangle index.
    const int tblk = (blockIdx.x & 7) * 66 + (blockIdx.x >> 3);
    int bi = (int)(32.5f - sqrtf(32.5f * 32.5f - 2.0f * (float)tblk));
    while (bi * (65 - bi) / 2 > tblk) --bi;
    while ((bi + 1) * (64 - bi) / 2 <= tblk) ++bi;
    const int bj = bi + (tblk - bi * (65 - bi) / 2);
    const bool diag = (bi == bj);

    const int t = threadIdx.x;
    const int iBase = bi * 256, jBase = bj * 256;
    const int lane = t & 63, wave = t >> 6;
    const int wm = wave >> 2, wn = wave & 3;  // wave grid 2 x 4
    const int lrow = lane & 15, quad = lane >> 4;

    // Staging role: wave w covers combined rows w*64..w*64+63 (A then B).
    const int sBase = (wave < 4) ? (iBase + wave * 64) : (jBase + (wave - 4) * 64);
    const size_t gRow0 = (size_t)(sBase + lane) * 16;
    const int ldsRow0 = wave * 64;  // 0..511
    uint8_t* buf0 = smem;
    uint8_t* buf1 = smem + 65536;

    f32x4 acc[8][4] = {};

    // Prologue: k-step 0 (units 0..7) into buffer 0.
#pragma unroll
    for (int u = 0; u < 8; ++u)
        gload_lds16(f8t + (size_t)u * UST + gRow0,
                    buf0 + u * 8192 + ldsRow0 * 16);

#pragma unroll
    for (int kk = 0; kk < 4; ++kk) {
        uint8_t* curb = (kk & 1) ? buf1 : buf0;
        uint8_t* nxtb = (kk & 1) ? buf0 : buf1;
        __syncthreads();
        if (kk < 3) {
#pragma unroll
            for (int u = 0; u < 8; ++u)
                gload_lds16(f8t + (size_t)(8 * (kk + 1) + u) * UST + gRow0,
                            nxtb + u * 8192 + ldsRow0 * 16);
        }
        // B fragments (held across the m-loop), A fragment re-read per m.
        const uint8_t* ubase = curb + (2 * quad) * 8192;
        i32x8 bv[4];
#pragma unroll
        for (int n = 0; n < 4; ++n) {
            const uint8_t* base = ubase + (256 + wn * 64 + n * 16 + lrow) * 16;
            i32x4 lo = *(const i32x4*)base;
            i32x4 hi = *(const i32x4*)(base + 8192);
            bv[n] = __builtin_shufflevector(lo, hi, 0, 1, 2, 3, 4, 5, 6, 7);
        }
#pragma unroll
        for (int m = 0; m < 8; ++m) {
            const uint8_t* base = ubase + (wm * 128 + m * 16 + lrow) * 16;
            i32x4 lo = *(const i32x4*)base;
            i32x4 hi = *(const i32x4*)(base + 8192);
            i32x8 av = __builtin_shufflevector(lo, hi, 0, 1, 2, 3, 4, 5, 6, 7);
#pragma unroll
            for (int n = 0; n < 4; ++n)
                acc[m][n] = __builtin_amdgcn_mfma_scale_f32_16x16x128_f8f6f4(
                    av, bv[n], acc[m][n], 0, 0,
                    0, 0x7F7F7F7F, 0, 0x7F7F7F7F);  // E8M0 1.0 scales
        }
    }

    // Register-only epilogue. C/D: col=lane&15, row=quad*4+e (16x16 layout).
    // Row-side: slotR = 4*bj + wn, rows iBase + wm*128 + m*16 + quad*4 + e.
    // Col-side: slotC = 4*bi + 2*wm + h (h = m>>2), per 128-row half-strip.
    // Disjoint (col slots < 4*bi_r <= row slots) and 4(32-bi_r)+4bi_r = 128
    // slots per row covered exactly once.
    int labj[4];
#pragma unroll
    for (int n = 0; n < 4; ++n) labj[n] = lab[jBase + wn * 64 + n * 16 + lrow];

    const int slotR = 4 * bj + wn;
    float Ec[2][4] = {{0, 0, 0, 0}, {0, 0, 0, 0}};
    float Pc[2][4] = {{0, 0, 0, 0}, {0, 0, 0, 0}};

#pragma unroll
    for (int m = 0; m < 8; ++m) {
        const int h = m >> 2;
        const int rbase = wm * 128 + m * 16 + quad * 4;
        const int4 li4 = *(const int4*)(lab + iBase + rbase);
        float rE[4], rP[4];
#pragma unroll
        for (int e = 0; e < 4; ++e) {
            const int labi = ((const int*)&li4)[e];
            float se = 0.0f, sp = 0.0f;
            if (diag) {
                const int i = iBase + rbase + e;
#pragma unroll
                for (int n = 0; n < 4; ++n) {
                    const int j = jBase + wn * 64 + n * 16 + lrow;
                    const float tv = acc[m][n][e];
                    if (j != i) {
                        se += __expf(tv * SIM_SCALE);
                        if (labj[n] == labi) sp += tv;
                    }
                }
            } else {
#pragma unroll
                for (int n = 0; n < 4; ++n) {
                    const float tv = acc[m][n][e];
                    const float ex = __expf(tv * SIM_SCALE);
                    se += ex;
                    Ec[h][n] += ex;
                    if (labj[n] == labi) {
                        sp += tv;
                        Pc[h][n] += tv;
                    }
                }
            }
            rE[e] = rowsum16(se);
            rP[e] = rowsum16(sp) * SIM_SCALE;
        }
        if (lrow == 0) {
            // 4 consecutive rows -> 32B contiguous (two float4 stores)
            float2* dst = &PEP[(size_t)slotR * N_ROWS + iBase + rbase];
            float4 v0 = {rE[0], rP[0], rE[1], rP[1]};
            float4 v1 = {rE[2], rP[2], rE[3], rP[3]};
            *(float4*)dst = v0;
            *(float4*)(dst + 2) = v1;
        }
    }

    if (!diag) {
#pragma unroll
        for (int h = 0; h < 2; ++h)
#pragma unroll
            for (int n = 0; n < 4; ++n) {
                Ec[h][n] += __shfl_xor(Ec[h][n], 16, 64);
                Ec[h][n] += __shfl_xor(Ec[h][n], 32, 64);
                Pc[h][n] += __shfl_xor(Pc[h][n], 16, 64);
                Pc[h][n] += __shfl_xor(Pc[h][n], 32, 64);
            }
        if (quad == 0) {
            // 16 lanes x consecutive j -> 128B contiguous per (h, n)
#pragma unroll
            for (int h = 0; h < 2; ++h) {
                const int slotC = 4 * bi + 2 * wm + h;
#pragma unroll
                for (int n = 0; n < 4; ++n) {
                    const int j = jBase + wn * 64 + n * 16 + lrow;
                    float2 v;
                    v.x = Ec[h][n];
                    v.y = Pc[h][n] * SIM_SCALE;
                    PEP[(size_t)slotC * N_ROWS + j] = v;
                }
            }
        }
    }
}

// 128 blocks x 64 rows, [slot][row] layout; coalesced 512B wave reads.
__global__ __launch_bounds__(256) void final_kernel(const float2* __restrict__ PEP,
                                                    const int* __restrict__ lab,
                                                    float* __restrict__ out) {
    __shared__ float sE[256], sP[256], sh[4];
    __shared__ float shc;
    const int t = threadIdx.x;
    const int rr = t & 63, q = t >> 6;

    int cl = 0;
#pragma unroll 8
    for (int s = t; s < N_ROWS; s += 256) cl += lab[s];
#pragma unroll
    for (int off = 32; off >= 1; off >>= 1) cl += __shfl_xor(cl, off, 64);
    if (rr == 0) sh[q] = (float)cl;
    __syncthreads();
    if (t == 0) shc = sh[0] + sh[1] + sh[2] + sh[3];

    const int r0 = blockIdx.x * 64;
    float se = 0.0f, sp = 0.0f;
#pragma unroll 8
    for (int v = 0; v < 32; ++v) {
        const float2 x = PEP[(size_t)(q * 32 + v) * N_ROWS + r0 + rr];
        se += x.x;
        sp += x.y;
    }
    sE[t] = se;
    sP[t] = sp;
    __syncthreads();

    float local = 0.0f;
    if (q == 0) {
        se = sE[rr] + sE[64 + rr] + sE[128 + rr] + sE[192 + rr];
        sp = sP[rr] + sP[64 + rr] + sP[128 + rr] + sP[192 + rr];
        const float c1 = shc;
        const int li = lab[r0 + rr];
        const float np = (li ? c1 : (float)N_ROWS - c1) - 1.0f;
        local = (np * __logf(se) - sp) / (np + 1e-8f);
#pragma unroll
        for (int off = 32; off >= 1; off >>= 1) local += __shfl_xor(local, off, 64);
    }
    if (t == 0) atomicAdd(out, local * (1.0f / (float)N_ROWS));
}

extern "C" void kernel_launch(void* const* d_in, const int* in_sizes, int n_in,
                              void* d_out, int out_size, void* d_ws, size_t ws_size,
                              hipStream_t stream) {
    const float* features = (const float*)d_in[0];
    const int* labels = (const int*)d_in[1];
    float* out = (float*)d_out;

    char* ws = (char*)d_ws;
    uint8_t* f8t = (uint8_t*)ws;                             // 4 MiB transposed
    float2* PEP = (float2*)(ws + (size_t)N_ROWS * DIMB);     // 8 MiB [slot][row]

    static bool smem_ok = false;
    if (!smem_ok) {
        hipFuncSetAttribute(reinterpret_cast<const void*>(sim_kernel),
                            hipFuncAttributeMaxDynamicSharedMemorySize, 131072);
        smem_ok = true;
    }

    norm_kernel<<<N_ROWS / 4, 256, 0, stream>>>(features, f8t, out);
    sim_kernel<<<NB2 * (NB2 + 1) / 2, 512, 131072, stream>>>(f8t, labels, PEP);
    final_kernel<<<128, 256, 0, stream>>>(PEP, labels, out);
}

// Round 9
// 155.234 us; speedup vs baseline: 1.0014x; 1.0014x over previous
//
#include <hip/hip_runtime.h>
#include <hip/hip_bf16.h>
#include <stdint.h>

// ContrastiveLoss: N=8192, D=512 fp32 features, int labels {0,1}.
// out = mean_i [ (np_i * log(sum_exp_i) - sum_pos_i) / (np_i + 1e-8) ]
// R1..R19: fp8 128^2 tiles, upper-tri, XCD swizzle, gload_lds, [slot][row]
//     PEP, DPP epilogue. 109.5 us (sim ~45).
// R22: MX 32x32x64 correct but bank-conflicted (-11). R23: transposed
//     f8t[unit][row][16B] + unit-major LDS + MX 16x16x128: conflicts gone,
//     107.4 us champion, sim ~43.
// R24: 256^2 tiles (528 blocks, 8 waves, BK=128, 128KB dynamic LDS) ->
//     sim 85.7 us REGRESSION. Counters: WRITE 8->110 MB, FETCH 15->74 MB,
//     VGPR_Count=128 (= acc size alone) -> dynamic LDS hid the occupancy
//     constraint from regalloc; it capped at 128 VGPR and spilled the
//     whole accumulator to scratch. Amortization theory untested.
// R25: single fix -- __launch_bounds__(512, 2): 2 waves/EU = 256 VGPR cap
//     (live set ~200, zero spill), matches the LDS-forced 1 block/CU
//     anyway. Everything else identical to R24.

#define N_ROWS 8192
#define DIMF 512
#define DIMB 512
#define NB2 32
#define NSLOT 128
#define SIM_SCALE 0.0390625f   // 10 / 256  (features pre-scaled by 16)
#define UST (8192 * 16)        // f8t unit stride: one 16B unit for all rows

typedef float f32x4 __attribute__((ext_vector_type(4)));
typedef int i32x4 __attribute__((ext_vector_type(4)));
typedef int i32x8 __attribute__((ext_vector_type(8)));

__device__ static inline void gload_lds16(const uint8_t* g, uint8_t* l) {
    __builtin_amdgcn_global_load_lds(
        (const __attribute__((address_space(1))) unsigned int*)g,
        (__attribute__((address_space(3))) unsigned int*)l, 16, 0, 0);
}

// 16-lane rotate-reduce (VALU DPP row_ror, no LDS pipe). Proven R19.
__device__ static inline float rowsum16(float s) {
    s += __int_as_float(__builtin_amdgcn_update_dpp(
        0, __float_as_int(s), 0x128, 0xf, 0xf, false));
    s += __int_as_float(__builtin_amdgcn_update_dpp(
        0, __float_as_int(s), 0x124, 0xf, 0xf, false));
    s += __int_as_float(__builtin_amdgcn_update_dpp(
        0, __float_as_int(s), 0x122, 0xf, 0xf, false));
    s += __int_as_float(__builtin_amdgcn_update_dpp(
        0, __float_as_int(s), 0x121, 0xf, 0xf, false));
    return s;
}

// 4 waves/block, one row per wave: fp32 sumsq -> scale by 16/norm -> fp8.
// Output layout: f8t[g][row][16B], g = dim>>4 (unit-major transposed).
__global__ __launch_bounds__(256) void norm_kernel(const float* __restrict__ x,
                                                   uint8_t* __restrict__ f8t,
                                                   float* __restrict__ out) {
    const int wave = threadIdx.x >> 6, t = threadIdx.x & 63;
    const int row = blockIdx.x * 4 + wave;
    const float4* xr = (const float4*)(x + (size_t)row * DIMF);
    float4 v0 = xr[2 * t];
    float4 v1 = xr[2 * t + 1];
    float ss = v0.x * v0.x + v0.y * v0.y + v0.z * v0.z + v0.w * v0.w +
               v1.x * v1.x + v1.y * v1.y + v1.z * v1.z + v1.w * v1.w;
#pragma unroll
    for (int off = 32; off >= 1; off >>= 1) ss += __shfl_xor(ss, off, 64);
    float s = 16.0f / fmaxf(sqrtf(ss), 1e-12f);
    int lo = 0, hi = 0;
    lo = __builtin_amdgcn_cvt_pk_fp8_f32(v0.x * s, v0.y * s, lo, false);
    lo = __builtin_amdgcn_cvt_pk_fp8_f32(v0.z * s, v0.w * s, lo, true);
    hi = __builtin_amdgcn_cvt_pk_fp8_f32(v1.x * s, v1.y * s, hi, false);
    hi = __builtin_amdgcn_cvt_pk_fp8_f32(v1.z * s, v1.w * s, hi, true);
    int2 pk;
    pk.x = lo;
    pk.y = hi;
    *(int2*)(f8t + (size_t)(t >> 1) * UST + (size_t)row * 16 + (t & 1) * 8) = pk;
    if (blockIdx.x == 0 && threadIdx.x == 0) out[0] = 0.0f;
}

// 256x256 tile/block, 8 waves (2x4), each 128x64 via 8x4 MFMA 16x16x128
// MX-fp8 (uniform 1.0 E8M0 scales -> exact; A/B operand symmetry makes any
// consistent k-mapping exact). BK=128B (8 units/step, 4 steps), 2-buffer
// __syncthreads pipeline, 128KB dynamic LDS: per buffer [8 units][512
// rows][16B] (rows 0-255 = A-tile, 256-511 = B-tile). Staging: wave w
// stages rows w*64..w*64+63 of the combined space for all 8 units --
// contiguous 1024B wave-writes. Fragment reads: contiguous 16B/lane over
// rows (2-way bank tier, free).
__global__ __launch_bounds__(512, 2) void sim_kernel(const uint8_t* __restrict__ f8t,
                                                     const int* __restrict__ lab,
                                                     float2* __restrict__ PEP) {
    extern __shared__ uint8_t smem[];

    // XCD-locality swizzle (528 = 8 * 66); decode upper-triangle index.
    const int tblk = (blockIdx.x & 7) * 66 + (blockIdx.x >> 3);
    int bi = (int)(32.5f - sqrtf(32.5f * 32.5f - 2.0f * (float)tblk));
    while (bi * (65 - bi) / 2 > tblk) --bi;
    while ((bi + 1) * (64 - bi) / 2 <= tblk) ++bi;
    const int bj = bi + (tblk - bi * (65 - bi) / 2);
    const bool diag = (bi == bj);

    const int t = threadIdx.x;
    const int iBase = bi * 256, jBase = bj * 256;
    const int lane = t & 63, wave = t >> 6;
    const int wm = wave >> 2, wn = wave & 3;  // wave grid 2 x 4
    const int lrow = lane & 15, quad = lane >> 4;

    // Staging role: wave w covers combined rows w*64..w*64+63 (A then B).
    const int sBase = (wave < 4) ? (iBase + wave * 64) : (jBase + (wave - 4) * 64);
    const size_t gRow0 = (size_t)(sBase + lane) * 16;
    const int ldsRow0 = wave * 64;  // 0..511
    uint8_t* buf0 = smem;
    uint8_t* buf1 = smem + 65536;

    f32x4 acc[8][4] = {};

    // Prologue: k-step 0 (units 0..7) into buffer 0.
#pragma unroll
    for (int u = 0; u < 8; ++u)
        gload_lds16(f8t + (size_t)u * UST + gRow0,
                    buf0 + u * 8192 + ldsRow0 * 16);

#pragma unroll
    for (int kk = 0; kk < 4; ++kk) {
        uint8_t* curb = (kk & 1) ? buf1 : buf0;
        uint8_t* nxtb = (kk & 1) ? buf0 : buf1;
        __syncthreads();
        if (kk < 3) {
#pragma unroll
            for (int u = 0; u < 8; ++u)
                gload_lds16(f8t + (size_t)(8 * (kk + 1) + u) * UST + gRow0,
                            nxtb + u * 8192 + ldsRow0 * 16);
        }
        // B fragments (held across the m-loop), A fragment re-read per m.
        const uint8_t* ubase = curb + (2 * quad) * 8192;
        i32x8 bv[4];
#pragma unroll
        for (int n = 0; n < 4; ++n) {
            const uint8_t* base = ubase + (256 + wn * 64 + n * 16 + lrow) * 16;
            i32x4 lo = *(const i32x4*)base;
            i32x4 hi = *(const i32x4*)(base + 8192);
            bv[n] = __builtin_shufflevector(lo, hi, 0, 1, 2, 3, 4, 5, 6, 7);
        }
#pragma unroll
        for (int m = 0; m < 8; ++m) {
            const uint8_t* base = ubase + (wm * 128 + m * 16 + lrow) * 16;
            i32x4 lo = *(const i32x4*)base;
            i32x4 hi = *(const i32x4*)(base + 8192);
            i32x8 av = __builtin_shufflevector(lo, hi, 0, 1, 2, 3, 4, 5, 6, 7);
#pragma unroll
            for (int n = 0; n < 4; ++n)
                acc[m][n] = __builtin_amdgcn_mfma_scale_f32_16x16x128_f8f6f4(
                    av, bv[n], acc[m][n], 0, 0,
                    0, 0x7F7F7F7F, 0, 0x7F7F7F7F);  // E8M0 1.0 scales
        }
    }

    // Register-only epilogue. C/D: col=lane&15, row=quad*4+e (16x16 layout).
    // Row-side: slotR = 4*bj + wn, rows iBase + wm*128 + m*16 + quad*4 + e.
    // Col-side: slotC = 4*bi + 2*wm + h (h = m>>2), per 128-row half-strip.
    // Disjoint (col slots < 4*bi_r <= row slots) and 4(32-bi_r)+4bi_r = 128
    // slots per row covered exactly once.
    int labj[4];
#pragma unroll
    for (int n = 0; n < 4; ++n) labj[n] = lab[jBase + wn * 64 + n * 16 + lrow];

    const int slotR = 4 * bj + wn;
    float Ec[2][4] = {{0, 0, 0, 0}, {0, 0, 0, 0}};
    float Pc[2][4] = {{0, 0, 0, 0}, {0, 0, 0, 0}};

#pragma unroll
    for (int m = 0; m < 8; ++m) {
        const int h = m >> 2;
        const int rbase = wm * 128 + m * 16 + quad * 4;
        const int4 li4 = *(const int4*)(lab + iBase + rbase);
        float rE[4], rP[4];
#pragma unroll
        for (int e = 0; e < 4; ++e) {
            const int labi = ((const int*)&li4)[e];
            float se = 0.0f, sp = 0.0f;
            if (diag) {
                const int i = iBase + rbase + e;
#pragma unroll
                for (int n = 0; n < 4; ++n) {
                    const int j = jBase + wn * 64 + n * 16 + lrow;
                    const float tv = acc[m][n][e];
                    if (j != i) {
                        se += __expf(tv * SIM_SCALE);
                        if (labj[n] == labi) sp += tv;
                    }
                }
            } else {
#pragma unroll
                for (int n = 0; n < 4; ++n) {
                    const float tv = acc[m][n][e];
                    const float ex = __expf(tv * SIM_SCALE);
                    se += ex;
                    Ec[h][n] += ex;
                    if (labj[n] == labi) {
                        sp += tv;
                        Pc[h][n] += tv;
                    }
                }
            }
            rE[e] = rowsum16(se);
            rP[e] = rowsum16(sp) * SIM_SCALE;
        }
        if (lrow == 0) {
            // 4 consecutive rows -> 32B contiguous (two float4 stores)
            float2* dst = &PEP[(size_t)slotR * N_ROWS + iBase + rbase];
            float4 v0 = {rE[0], rP[0], rE[1], rP[1]};
            float4 v1 = {rE[2], rP[2], rE[3], rP[3]};
            *(float4*)dst = v0;
            *(float4*)(dst + 2) = v1;
        }
    }

    if (!diag) {
#pragma unroll
        for (int h = 0; h < 2; ++h)
#pragma unroll
            for (int n = 0; n < 4; ++n) {
                Ec[h][n] += __shfl_xor(Ec[h][n], 16, 64);
                Ec[h][n] += __shfl_xor(Ec[h][n], 32, 64);
                Pc[h][n] += __shfl_xor(Pc[h][n], 16, 64);
                Pc[h][n] += __shfl_xor(Pc[h][n], 32, 64);
            }
        if (quad == 0) {
            // 16 lanes x consecutive j -> 128B contiguous per (h, n)
#pragma unroll
            for (int h = 0; h < 2; ++h) {
                const int slotC = 4 * bi + 2 * wm + h;
#pragma unroll
                for (int n = 0; n < 4; ++n) {
                    const int j = jBase + wn * 64 + n * 16 + lrow;
                    float2 v;
                    v.x = Ec[h][n];
                    v.y = Pc[h][n] * SIM_SCALE;
                    PEP[(size_t)slotC * N_ROWS + j] = v;
                }
            }
        }
    }
}

// 128 blocks x 64 rows, [slot][row] layout; coalesced 512B wave reads.
__global__ __launch_bounds__(256) void final_kernel(const float2* __restrict__ PEP,
                                                    const int* __restrict__ lab,
                                                    float* __restrict__ out) {
    __shared__ float sE[256], sP[256], sh[4];
    __shared__ float shc;
    const int t = threadIdx.x;
    const int rr = t & 63, q = t >> 6;

    int cl = 0;
#pragma unroll 8
    for (int s = t; s < N_ROWS; s += 256) cl += lab[s];
#pragma unroll
    for (int off = 32; off >= 1; off >>= 1) cl += __shfl_xor(cl, off, 64);
    if (rr == 0) sh[q] = (float)cl;
    __syncthreads();
    if (t == 0) shc = sh[0] + sh[1] + sh[2] + sh[3];

    const int r0 = blockIdx.x * 64;
    float se = 0.0f, sp = 0.0f;
#pragma unroll 8
    for (int v = 0; v < 32; ++v) {
        const float2 x = PEP[(size_t)(q * 32 + v) * N_ROWS + r0 + rr];
        se += x.x;
        sp += x.y;
    }
    sE[t] = se;
    sP[t] = sp;
    __syncthreads();

    float local = 0.0f;
    if (q == 0) {
        se = sE[rr] + sE[64 + rr] + sE[128 + rr] + sE[192 + rr];
        sp = sP[rr] + sP[64 + rr] + sP[128 + rr] + sP[192 + rr];
        const float c1 = shc;
        const int li = lab[r0 + rr];
        const float np = (li ? c1 : (float)N_ROWS - c1) - 1.0f;
        local = (np * __logf(se) - sp) / (np + 1e-8f);
#pragma unroll
        for (int off = 32; off >= 1; off >>= 1) local += __shfl_xor(local, off, 64);
    }
    if (t == 0) atomicAdd(out, local * (1.0f / (float)N_ROWS));
}

extern "C" void kernel_launch(void* const* d_in, const int* in_sizes, int n_in,
                              void* d_out, int out_size, void* d_ws, size_t ws_size,
                              hipStream_t stream) {
    const float* features = (const float*)d_in[0];
    const int* labels = (const int*)d_in[1];
    float* out = (float*)d_out;

    char* ws = (char*)d_ws;
    uint8_t* f8t = (uint8_t*)ws;                             // 4 MiB transposed
    float2* PEP = (float2*)(ws + (size_t)N_ROWS * DIMB);     // 8 MiB [slot][row]

    static bool smem_ok = false;
    if (!smem_ok) {
        hipFuncSetAttribute(reinterpret_cast<const void*>(sim_kernel),
                            hipFuncAttributeMaxDynamicSharedMemorySize, 131072);
        smem_ok = true;
    }

    norm_kernel<<<N_ROWS / 4, 256, 0, stream>>>(features, f8t, out);
    sim_kernel<<<NB2 * (NB2 + 1) / 2, 512, 131072, stream>>>(f8t, labels, PEP);
    final_kernel<<<128, 256, 0, stream>>>(PEP, labels, out);
}

// Round 12
// 122.106 us; speedup vs baseline: 1.2730x; 1.2713x over previous
//
#include <hip/hip_runtime.h>
#include <hip/hip_bf16.h>
#include <stdint.h>

// ContrastiveLoss: N=8192, D=512 fp32 features, int labels {0,1}.
// out = mean_i [ (np_i * log(sum_exp_i) - sum_pos_i) / (np_i + 1e-8) ]
// R23 champion (107.4 us): 128^2 tiles, transposed f8t[unit][row][16B],
//     unit-major LDS, MX 16x16x128 (1.0 scales, exact by A/B symmetry),
//     BK=128 2-buffer pipeline, DPP epilogue, [slot][row] PEP.
// R24-R27: 256^2 line abandoned (2 spill-regressions: dynamic-LDS hid the
//     occupancy constraint -> 128-VGPR cap -> acc spilled; 2 container
//     failures on the attempted fixes: static 128K LDS / waves_per_eu).
// R28: attack the measured stall-domination instead: busiest pipe only
//     ~33% of sim wall-clock (MFMA 7us, LDS 13us, VALU 14us of 43us) at
//     just 8 waves/CU. Double concurrency: 512 threads / 8 waves per
//     128^2 block (wave grid 2x4, per-wave 64x32 = 4x2 MFMA). Live VGPR
//     ~90-110 < 128 cap BY DESIGN (R24 lesson inverted). 16 waves/CU.
//     NSLOT=256: slotR=4*bj+wn, slotC=4*bi+2*wm+h (h=m>>1); coverage
//     (64-bi)*4 + bi*4 = 256 const, disjoint, exact. PEP 16 MiB.

#define N_ROWS 8192
#define DIMF 512
#define DIMB 512
#define NB 64
#define NSLOT 256
#define SIM_SCALE 0.0390625f   // 10 / 256  (features pre-scaled by 16)
#define UST (8192 * 16)        // f8t unit stride: one 16B unit for all rows

typedef float f32x4 __attribute__((ext_vector_type(4)));
typedef int i32x4 __attribute__((ext_vector_type(4)));
typedef int i32x8 __attribute__((ext_vector_type(8)));

__device__ static inline void gload_lds16(const uint8_t* g, uint8_t* l) {
    __builtin_amdgcn_global_load_lds(
        (const __attribute__((address_space(1))) unsigned int*)g,
        (__attribute__((address_space(3))) unsigned int*)l, 16, 0, 0);
}

// 16-lane rotate-reduce (VALU DPP row_ror, no LDS pipe). Proven R19.
__device__ static inline float rowsum16(float s) {
    s += __int_as_float(__builtin_amdgcn_update_dpp(
        0, __float_as_int(s), 0x128, 0xf, 0xf, false));
    s += __int_as_float(__builtin_amdgcn_update_dpp(
        0, __float_as_int(s), 0x124, 0xf, 0xf, false));
    s += __int_as_float(__builtin_amdgcn_update_dpp(
        0, __float_as_int(s), 0x122, 0xf, 0xf, false));
    s += __int_as_float(__builtin_amdgcn_update_dpp(
        0, __float_as_int(s), 0x121, 0xf, 0xf, false));
    return s;
}

// 4 waves/block, one row per wave: fp32 sumsq -> scale by 16/norm -> fp8.
// Output layout: f8t[g][row][16B], g = dim>>4 (unit-major transposed).
__global__ __launch_bounds__(256) void norm_kernel(const float* __restrict__ x,
                                                   uint8_t* __restrict__ f8t,
                                                   float* __restrict__ out) {
    const int wave = threadIdx.x >> 6, t = threadIdx.x & 63;
    const int row = blockIdx.x * 4 + wave;
    const float4* xr = (const float4*)(x + (size_t)row * DIMF);
    float4 v0 = xr[2 * t];
    float4 v1 = xr[2 * t + 1];
    float ss = v0.x * v0.x + v0.y * v0.y + v0.z * v0.z + v0.w * v0.w +
               v1.x * v1.x + v1.y * v1.y + v1.z * v1.z + v1.w * v1.w;
#pragma unroll
    for (int off = 32; off >= 1; off >>= 1) ss += __shfl_xor(ss, off, 64);
    float s = 16.0f / fmaxf(sqrtf(ss), 1e-12f);
    int lo = 0, hi = 0;
    lo = __builtin_amdgcn_cvt_pk_fp8_f32(v0.x * s, v0.y * s, lo, false);
    lo = __builtin_amdgcn_cvt_pk_fp8_f32(v0.z * s, v0.w * s, lo, true);
    hi = __builtin_amdgcn_cvt_pk_fp8_f32(v1.x * s, v1.y * s, hi, false);
    hi = __builtin_amdgcn_cvt_pk_fp8_f32(v1.z * s, v1.w * s, hi, true);
    int2 pk;
    pk.x = lo;
    pk.y = hi;
    *(int2*)(f8t + (size_t)(t >> 1) * UST + (size_t)row * 16 + (t & 1) * 8) = pk;
    if (blockIdx.x == 0 && threadIdx.x == 0) out[0] = 0.0f;
}

// 128x128 tile/block, 8 waves (2x4), each 64x32 via 4x2 MFMA 16x16x128
// MX-fp8 (uniform 1.0 E8M0 scales -> exact). BK=128B (8 units/step, 4
// steps), 2-buffer __syncthreads pipeline, 64KB static LDS (R23 layout:
// [unit][row][16B] per side per buffer). Staging: wave (side, half, pair)
// stages units 4*pair..4*pair+3 at rows half*64..half*64+63 -> 4 gloads
// of contiguous 1024B. Fragment reads: quad -> units {2q, 2q+1},
// contiguous rows: 8 lanes per 4-bank group x 8 groups = fully packed,
// conflict-free.
__global__ __launch_bounds__(512) void sim_kernel(const uint8_t* __restrict__ f8t,
                                                  const int* __restrict__ lab,
                                                  float2* __restrict__ PEP) {
    __shared__ __align__(16) uint8_t sA[2][8 * 128 * 16];
    __shared__ __align__(16) uint8_t sB[2][8 * 128 * 16];

    // XCD-locality swizzle (2080 = 8 * 260); decode upper-triangle index.
    const int tblk = (blockIdx.x & 7) * 260 + (blockIdx.x >> 3);
    int bi = (int)(64.5f - sqrtf(64.5f * 64.5f - 2.0f * (float)tblk));
    while (bi * (129 - bi) / 2 > tblk) --bi;
    while ((bi + 1) * (128 - bi) / 2 <= tblk) ++bi;
    const int bj = bi + (tblk - bi * (129 - bi) / 2);
    const bool diag = (bi == bj);

    const int t = threadIdx.x;
    const int iBase = bi * 128, jBase = bj * 128;
    const int lane = t & 63, wave = t >> 6;
    const int wm = wave >> 2, wn = wave & 3;  // wave grid 2 x 4
    const int lrow = lane & 15, quad = lane >> 4;

    // Staging role: side = wave>>2, half = (wave>>1)&1, pair = wave&1.
    const int side = wave >> 2, shalf = (wave >> 1) & 1, pair = wave & 1;
    const size_t gRow0 =
        (size_t)((side ? jBase : iBase) + shalf * 64 + lane) * 16;
    const int dstOff = pair * 4 * 2048 + shalf * 1024;
    uint8_t* sS0 = (side ? sB[0] : sA[0]) + dstOff;
    uint8_t* sS1 = (side ? sB[1] : sA[1]) + dstOff;

    f32x4 acc[4][2] = {};

    // Prologue: k-step 0 (units 0..7) into buffer 0.
#pragma unroll
    for (int c = 0; c < 4; ++c)
        gload_lds16(f8t + (size_t)(4 * pair + c) * UST + gRow0, sS0 + c * 2048);

#pragma unroll
    for (int kk = 0; kk < 4; ++kk) {
        const int cur = kk & 1;
        __syncthreads();
        if (kk < 3) {
            uint8_t* dst = cur ? sS0 : sS1;
#pragma unroll
            for (int c = 0; c < 4; ++c)
                gload_lds16(
                    f8t + (size_t)(8 * (kk + 1) + 4 * pair + c) * UST + gRow0,
                    dst + c * 2048);
        }
        // B fragments held (bv[2], 4 reads); A fragment re-read per m.
        const uint8_t* au = sA[cur] + (2 * quad) * 2048;
        const uint8_t* bu = sB[cur] + (2 * quad) * 2048;
        i32x8 bv[2];
#pragma unroll
        for (int n = 0; n < 2; ++n) {
            const uint8_t* base = bu + (wn * 32 + n * 16 + lrow) * 16;
            i32x4 lo = *(const i32x4*)base;
            i32x4 hi = *(const i32x4*)(base + 2048);
            bv[n] = __builtin_shufflevector(lo, hi, 0, 1, 2, 3, 4, 5, 6, 7);
        }
#pragma unroll
        for (int m = 0; m < 4; ++m) {
            const uint8_t* base = au + (wm * 64 + m * 16 + lrow) * 16;
            i32x4 lo = *(const i32x4*)base;
            i32x4 hi = *(const i32x4*)(base + 2048);
            i32x8 av = __builtin_shufflevector(lo, hi, 0, 1, 2, 3, 4, 5, 6, 7);
#pragma unroll
            for (int n = 0; n < 2; ++n)
                acc[m][n] = __builtin_amdgcn_mfma_scale_f32_16x16x128_f8f6f4(
                    av, bv[n], acc[m][n], 0, 0,
                    0, 0x7F7F7F7F, 0, 0x7F7F7F7F);  // E8M0 1.0 scales
        }
    }

    // Register-only epilogue. C/D: col=lane&15, row=quad*4+e (16x16 layout).
    // Row-side: slotR = 4*bj + wn (rows iBase + wm*64 + m*16 + quad*4 + e,
    // summed over this wave's 32 cols). Col-side: slotC = 4*bi + 2*wm + h
    // (h = m>>1: 32-row groups). Coverage per row: (64-bi)*4 + bi*4 = 256.
    int labj[2];
#pragma unroll
    for (int n = 0; n < 2; ++n) labj[n] = lab[jBase + wn * 32 + n * 16 + lrow];

    const int slotR = 4 * bj + wn;
    float Ec[2][2] = {{0, 0}, {0, 0}};
    float Pc[2][2] = {{0, 0}, {0, 0}};

#pragma unroll
    for (int m = 0; m < 4; ++m) {
        const int h = m >> 1;
        const int rbase = wm * 64 + m * 16 + quad * 4;
        const int4 li4 = *(const int4*)(lab + iBase + rbase);
        float rE[4], rP[4];
#pragma unroll
        for (int e = 0; e < 4; ++e) {
            const int labi = ((const int*)&li4)[e];
            float se = 0.0f, sp = 0.0f;
            if (diag) {
                const int i = iBase + rbase + e;
#pragma unroll
                for (int n = 0; n < 2; ++n) {
                    const int j = jBase + wn * 32 + n * 16 + lrow;
                    const float tv = acc[m][n][e];
                    if (j != i) {
                        se += __expf(tv * SIM_SCALE);
                        if (labj[n] == labi) sp += tv;
                    }
                }
            } else {
#pragma unroll
                for (int n = 0; n < 2; ++n) {
                    const float tv = acc[m][n][e];
                    const float ex = __expf(tv * SIM_SCALE);
                    se += ex;
                    Ec[h][n] += ex;
                    if (labj[n] == labi) {
                        sp += tv;
                        Pc[h][n] += tv;
                    }
                }
            }
            rE[e] = rowsum16(se);
            rP[e] = rowsum16(sp) * SIM_SCALE;
        }
        if (lrow == 0) {
            // 4 consecutive rows -> 32B contiguous (two float4 stores)
            float2* dst = &PEP[(size_t)slotR * N_ROWS + iBase + rbase];
            float4 v0 = {rE[0], rP[0], rE[1], rP[1]};
            float4 v1 = {rE[2], rP[2], rE[3], rP[3]};
            *(float4*)dst = v0;
            *(float4*)(dst + 2) = v1;
        }
    }

    if (!diag) {
#pragma unroll
        for (int h = 0; h < 2; ++h)
#pragma unroll
            for (int n = 0; n < 2; ++n) {
                Ec[h][n] += __shfl_xor(Ec[h][n], 16, 64);
                Ec[h][n] += __shfl_xor(Ec[h][n], 32, 64);
                Pc[h][n] += __shfl_xor(Pc[h][n], 16, 64);
                Pc[h][n] += __shfl_xor(Pc[h][n], 32, 64);
            }
        if (quad == 0) {
            // 16 lanes x consecutive j -> 128B contiguous per (h, n)
#pragma unroll
            for (int h = 0; h < 2; ++h) {
                const int slotC = 4 * bi + 2 * wm + h;
#pragma unroll
                for (int n = 0; n < 2; ++n) {
                    const int j = jBase + wn * 32 + n * 16 + lrow;
                    float2 v;
                    v.x = Ec[h][n];
                    v.y = Pc[h][n] * SIM_SCALE;
                    PEP[(size_t)slotC * N_ROWS + j] = v;
                }
            }
        }
    }
}

// 128 blocks x 64 rows, [slot][row] layout; coalesced 512B wave reads.
// NSLOT=256: each thread-quarter sums 64 slots.
__global__ __launch_bounds__(256) void final_kernel(const float2* __restrict__ PEP,
                                                    const int* __restrict__ lab,
                                                    float* __restrict__ out) {
    __shared__ float sE[256], sP[256], sh[4];
    __shared__ float shc;
    const int t = threadIdx.x;
    const int rr = t & 63, q = t >> 6;

    int cl = 0;
#pragma unroll 8
    for (int s = t; s < N_ROWS; s += 256) cl += lab[s];
#pragma unroll
    for (int off = 32; off >= 1; off >>= 1) cl += __shfl_xor(cl, off, 64);
    if (rr == 0) sh[q] = (float)cl;
    __syncthreads();
    if (t == 0) shc = sh[0] + sh[1] + sh[2] + sh[3];

    const int r0 = blockIdx.x * 64;
    float se = 0.0f, sp = 0.0f;
#pragma unroll 8
    for (int v = 0; v < 64; ++v) {
        const float2 x = PEP[(size_t)(q * 64 + v) * N_ROWS + r0 + rr];
        se += x.x;
        sp += x.y;
    }
    sE[t] = se;
    sP[t] = sp;
    __syncthreads();

    float local = 0.0f;
    if (q == 0) {
        se = sE[rr] + sE[64 + rr] + sE[128 + rr] + sE[192 + rr];
        sp = sP[rr] + sP[64 + rr] + sP[128 + rr] + sP[192 + rr];
        const float c1 = shc;
        const int li = lab[r0 + rr];
        const float np = (li ? c1 : (float)N_ROWS - c1) - 1.0f;
        local = (np * __logf(se) - sp) / (np + 1e-8f);
#pragma unroll
        for (int off = 32; off >= 1; off >>= 1) local += __shfl_xor(local, off, 64);
    }
    if (t == 0) atomicAdd(out, local * (1.0f / (float)N_ROWS));
}

extern "C" void kernel_launch(void* const* d_in, const int* in_sizes, int n_in,
                              void* d_out, int out_size, void* d_ws, size_t ws_size,
                              hipStream_t stream) {
    const float* features = (const float*)d_in[0];
    const int* labels = (const int*)d_in[1];
    float* out = (float*)d_out;

    char* ws = (char*)d_ws;
    uint8_t* f8t = (uint8_t*)ws;                             // 4 MiB transposed
    float2* PEP = (float2*)(ws + (size_t)N_ROWS * DIMB);     // 16 MiB [slot][row]

    norm_kernel<<<N_ROWS / 4, 256, 0, stream>>>(features, f8t, out);
    sim_kernel<<<NB * (NB + 1) / 2, 512, 0, stream>>>(f8t, labels, PEP);
    final_kernel<<<128, 256, 0, stream>>>(PEP, labels, out);
}

// Round 13
// 115.525 us; speedup vs baseline: 1.3456x; 1.0570x over previous
//
#include <hip/hip_runtime.h>
#include <hip/hip_bf16.h>
#include <stdint.h>

// ContrastiveLoss: N=8192, D=512 fp32 features, int labels {0,1}.
// out = mean_i [ (np_i * log(sum_exp_i) - sum_pos_i) / (np_i + 1e-8) ]
// R23 champion (107.4 us): 128^2 tiles, transposed f8t[unit][row][16B],
//     unit-major LDS, MX 16x16x128 (1.0 scales, exact by A/B operand
//     symmetry), BK=128 2-buffer pipeline, DPP epilogue, [slot][row] PEP.
// R24-R27: 256^2 line dead (spills / container kills). R28: 8 waves per
//     128^2 block -> sim 51.9 (WORSE: 1.5x LDS traffic, 2x epilogue VALU).
// Cumulative diagnosis: wall ~= SUM of pipe-busy times; barrier-lockstep
//     phases never overlap; every scheduling/occupancy tweak null or worse.
// R29: remove the disease, not the symptom: f8 matrix is 4 MiB = L2-fits
//     (guide m168/m169: staging L2-fit data is pure overhead). BARRIER-FREE
//     sim: fragments load straight from global into registers (f8t layout
//     makes them perfectly coalesced: 16 rows x 16B contiguous per quad).
//     Zero LDS, zero __syncthreads, K-loop = pure loads+MFMA, compiler
//     free-pipelines via vmcnt, 4 blocks/CU (16 waves). Epilogue, slots,
//     PEP, final: R23 verbatim.

#define N_ROWS 8192
#define DIMF 512
#define DIMB 512
#define NB 64
#define NSLOT 128
#define SIM_SCALE 0.0390625f   // 10 / 256  (features pre-scaled by 16)
#define UST (8192 * 16)        // f8t unit stride: one 16B unit for all rows

typedef float f32x4 __attribute__((ext_vector_type(4)));
typedef int i32x4 __attribute__((ext_vector_type(4)));
typedef int i32x8 __attribute__((ext_vector_type(8)));

// 16-lane rotate-reduce (VALU DPP row_ror, no LDS pipe). Proven R19.
__device__ static inline float rowsum16(float s) {
    s += __int_as_float(__builtin_amdgcn_update_dpp(
        0, __float_as_int(s), 0x128, 0xf, 0xf, false));
    s += __int_as_float(__builtin_amdgcn_update_dpp(
        0, __float_as_int(s), 0x124, 0xf, 0xf, false));
    s += __int_as_float(__builtin_amdgcn_update_dpp(
        0, __float_as_int(s), 0x122, 0xf, 0xf, false));
    s += __int_as_float(__builtin_amdgcn_update_dpp(
        0, __float_as_int(s), 0x121, 0xf, 0xf, false));
    return s;
}

// 4 waves/block, one row per wave: fp32 sumsq -> scale by 16/norm -> fp8.
// Output layout: f8t[g][row][16B], g = dim>>4 (unit-major transposed).
__global__ __launch_bounds__(256) void norm_kernel(const float* __restrict__ x,
                                                   uint8_t* __restrict__ f8t,
                                                   float* __restrict__ out) {
    const int wave = threadIdx.x >> 6, t = threadIdx.x & 63;
    const int row = blockIdx.x * 4 + wave;
    const float4* xr = (const float4*)(x + (size_t)row * DIMF);
    float4 v0 = xr[2 * t];
    float4 v1 = xr[2 * t + 1];
    float ss = v0.x * v0.x + v0.y * v0.y + v0.z * v0.z + v0.w * v0.w +
               v1.x * v1.x + v1.y * v1.y + v1.z * v1.z + v1.w * v1.w;
#pragma unroll
    for (int off = 32; off >= 1; off >>= 1) ss += __shfl_xor(ss, off, 64);
    float s = 16.0f / fmaxf(sqrtf(ss), 1e-12f);
    int lo = 0, hi = 0;
    lo = __builtin_amdgcn_cvt_pk_fp8_f32(v0.x * s, v0.y * s, lo, false);
    lo = __builtin_amdgcn_cvt_pk_fp8_f32(v0.z * s, v0.w * s, lo, true);
    hi = __builtin_amdgcn_cvt_pk_fp8_f32(v1.x * s, v1.y * s, hi, false);
    hi = __builtin_amdgcn_cvt_pk_fp8_f32(v1.z * s, v1.w * s, hi, true);
    int2 pk;
    pk.x = lo;
    pk.y = hi;
    *(int2*)(f8t + (size_t)(t >> 1) * UST + (size_t)row * 16 + (t & 1) * 8) = pk;
    if (blockIdx.x == 0 && threadIdx.x == 0) out[0] = 0.0f;
}

// 128x128 tile/block, 4 waves 2x2, each 64x64 via 4x4 MFMA 16x16x128
// MX-fp8 (uniform 1.0 E8M0 scales -> exact). NO LDS, NO barriers:
// fragments stream straight from global/L2. Per lane (lrow, quad):
// A frag m = rows iBase+wm*64+m*16+lrow, units {8kk+2q, 8kk+2q+1} ->
// two dwordx4 at pA + m*256 + kk*8*UST (+UST). Same formula for B ->
// operand symmetry -> any consistent k-map is exact (absmax 0.0, R22/23).
__global__ __launch_bounds__(256) void sim_kernel(const uint8_t* __restrict__ f8t,
                                                  const int* __restrict__ lab,
                                                  float2* __restrict__ PEP) {
    // XCD-locality swizzle (2080 = 8 * 260); decode upper-triangle index.
    const int tblk = (blockIdx.x & 7) * 260 + (blockIdx.x >> 3);
    int bi = (int)(64.5f - sqrtf(64.5f * 64.5f - 2.0f * (float)tblk));
    while (bi * (129 - bi) / 2 > tblk) --bi;
    while ((bi + 1) * (128 - bi) / 2 <= tblk) ++bi;
    const int bj = bi + (tblk - bi * (129 - bi) / 2);
    const bool diag = (bi == bj);

    const int t = threadIdx.x;
    const int iBase = bi * 128, jBase = bj * 128;
    const int lane = t & 63, wave = t >> 6;
    const int wm = wave >> 1, wn = wave & 1;
    const int lrow = lane & 15, quad = lane >> 4;

    const uint8_t* pA =
        f8t + (size_t)(2 * quad) * UST + (size_t)(iBase + wm * 64 + lrow) * 16;
    const uint8_t* pB =
        f8t + (size_t)(2 * quad) * UST + (size_t)(jBase + wn * 64 + lrow) * 16;

    f32x4 acc[4][4] = {};

#pragma unroll
    for (int kk = 0; kk < 4; ++kk) {
        const size_t ko = (size_t)(8 * kk) * UST;
        i32x8 av[4];
#pragma unroll
        for (int m = 0; m < 4; ++m) {
            const uint8_t* a = pA + ko + m * 256;
            i32x4 lo = *(const i32x4*)a;
            i32x4 hi = *(const i32x4*)(a + UST);
            av[m] = __builtin_shufflevector(lo, hi, 0, 1, 2, 3, 4, 5, 6, 7);
        }
#pragma unroll
        for (int n = 0; n < 4; ++n) {
            const uint8_t* b = pB + ko + n * 256;
            i32x4 lo = *(const i32x4*)b;
            i32x4 hi = *(const i32x4*)(b + UST);
            i32x8 bv = __builtin_shufflevector(lo, hi, 0, 1, 2, 3, 4, 5, 6, 7);
#pragma unroll
            for (int m = 0; m < 4; ++m)
                acc[m][n] = __builtin_amdgcn_mfma_scale_f32_16x16x128_f8f6f4(
                    av[m], bv, acc[m][n], 0, 0,
                    0, 0x7F7F7F7F, 0, 0x7F7F7F7F);  // E8M0 1.0 scales
        }
    }

    // Register-only epilogue (R23 verbatim). C/D: col=lane&15, row=quad*4+e.
    // sp/spc accumulate RAW acc; SIM_SCALE applied once after reductions.
    int labj[4];
#pragma unroll
    for (int n = 0; n < 4; ++n) labj[n] = lab[jBase + wn * 64 + n * 16 + lrow];

    const int slotR = 2 * bj + wn;  // rows of iBase
    const int slotC = 2 * bi + wm;  // cols of jBase
    float sec[4] = {0, 0, 0, 0}, spc[4] = {0, 0, 0, 0};

#pragma unroll
    for (int m = 0; m < 4; ++m) {
        const int rbase = wm * 64 + m * 16 + quad * 4;
        const int4 li4 = *(const int4*)(lab + iBase + rbase);
        float rE[4], rP[4];
#pragma unroll
        for (int e = 0; e < 4; ++e) {
            const int labi = ((const int*)&li4)[e];
            float se = 0.0f, sp = 0.0f;
            if (diag) {
                const int i = iBase + rbase + e;
#pragma unroll
                for (int n = 0; n < 4; ++n) {
                    const int j = jBase + wn * 64 + n * 16 + lrow;
                    const float tv = acc[m][n][e];
                    if (j != i) {
                        se += __expf(tv * SIM_SCALE);
                        if (labj[n] == labi) sp += tv;
                    }
                }
            } else {
#pragma unroll
                for (int n = 0; n < 4; ++n) {
                    const float tv = acc[m][n][e];
                    const float ex = __expf(tv * SIM_SCALE);
                    se += ex;
                    sec[n] += ex;
                    if (labj[n] == labi) {
                        sp += tv;
                        spc[n] += tv;
                    }
                }
            }
            rE[e] = rowsum16(se);
            rP[e] = rowsum16(sp) * SIM_SCALE;
        }
        if (lrow == 0) {
            // 4 consecutive rows -> 32B contiguous (two float4 stores)
            float2* dst = &PEP[(size_t)slotR * N_ROWS + iBase + rbase];
            float4 v0 = {rE[0], rP[0], rE[1], rP[1]};
            float4 v1 = {rE[2], rP[2], rE[3], rP[3]};
            *(float4*)dst = v0;
            *(float4*)(dst + 2) = v1;
        }
    }

    if (!diag) {
#pragma unroll
        for (int n = 0; n < 4; ++n) {
            sec[n] += __shfl_xor(sec[n], 16, 64);
            sec[n] += __shfl_xor(sec[n], 32, 64);
            spc[n] += __shfl_xor(spc[n], 16, 64);
            spc[n] += __shfl_xor(spc[n], 32, 64);
        }
        if (quad == 0) {
            // 16 lanes x consecutive j -> 128B contiguous per n
#pragma unroll
            for (int n = 0; n < 4; ++n) {
                const int j = jBase + wn * 64 + n * 16 + lrow;
                float2 v;
                v.x = sec[n];
                v.y = spc[n] * SIM_SCALE;
                PEP[(size_t)slotC * N_ROWS + j] = v;
            }
        }
    }
}

// 128 blocks x 64 rows, [slot][row] layout; coalesced 512B wave reads.
__global__ __launch_bounds__(256) void final_kernel(const float2* __restrict__ PEP,
                                                    const int* __restrict__ lab,
                                                    float* __restrict__ out) {
    __shared__ float sE[256], sP[256], sh[4];
    __shared__ float shc;
    const int t = threadIdx.x;
    const int rr = t & 63, q = t >> 6;

    int cl = 0;
#pragma unroll 8
    for (int s = t; s < N_ROWS; s += 256) cl += lab[s];
#pragma unroll
    for (int off = 32; off >= 1; off >>= 1) cl += __shfl_xor(cl, off, 64);
    if (rr == 0) sh[q] = (float)cl;
    __syncthreads();
    if (t == 0) shc = sh[0] + sh[1] + sh[2] + sh[3];

    const int r0 = blockIdx.x * 64;
    float se = 0.0f, sp = 0.0f;
#pragma unroll 8
    for (int v = 0; v < 32; ++v) {
        const float2 x = PEP[(size_t)(q * 32 + v) * N_ROWS + r0 + rr];
        se += x.x;
        sp += x.y;
    }
    sE[t] = se;
    sP[t] = sp;
    __syncthreads();

    float local = 0.0f;
    if (q == 0) {
        se = sE[rr] + sE[64 + rr] + sE[128 + rr] + sE[192 + rr];
        sp = sP[rr] + sP[64 + rr] + sP[128 + rr] + sP[192 + rr];
        const float c1 = shc;
        const int li = lab[r0 + rr];
        const float np = (li ? c1 : (float)N_ROWS - c1) - 1.0f;
        local = (np * __logf(se) - sp) / (np + 1e-8f);
#pragma unroll
        for (int off = 32; off >= 1; off >>= 1) local += __shfl_xor(local, off, 64);
    }
    if (t == 0) atomicAdd(out, local * (1.0f / (float)N_ROWS));
}

extern "C" void kernel_launch(void* const* d_in, const int* in_sizes, int n_in,
                              void* d_out, int out_size, void* d_ws, size_t ws_size,
                              hipStream_t stream) {
    const float* features = (const float*)d_in[0];
    const int* labels = (const int*)d_in[1];
    float* out = (float*)d_out;

    char* ws = (char*)d_ws;
    uint8_t* f8t = (uint8_t*)ws;                             // 4 MiB transposed
    float2* PEP = (float2*)(ws + (size_t)N_ROWS * DIMB);     // 8 MiB [slot][row]

    norm_kernel<<<N_ROWS / 4, 256, 0, stream>>>(features, f8t, out);
    sim_kernel<<<NB * (NB + 1) / 2, 256, 0, stream>>>(f8t, labels, PEP);
    final_kernel<<<128, 256, 0, stream>>>(PEP, labels, out);
}